// Round 8
// baseline (785.216 us; speedup 1.0000x reference)
//
#include <hip/hip_runtime.h>

namespace {
constexpr int N_NODES = 10000;
constexpr int DEG = 16;
constexpr int D = DEG + 1;            // 17 neighbors incl self-loop
constexpr int F_IN = 512;
constexpr int HID = 16;
constexpr int NC = 32;
constexpr int E0 = N_NODES * DEG;     // 160000
constexpr float SIGB  = 0.10009765625f;    // bf16(0.1)
constexpr float NORMB = 0.058837890625f;   // bf16(bf16(17^-0.5)^2)

// RNE f32->bf16 via gfx950 HW cvt
__device__ __forceinline__ float bfr(float v) {
  unsigned r;
  asm("v_cvt_pk_bf16_f32 %0, %1, %2" : "=v"(r) : "v"(v), "v"(v));
  return __uint_as_float(r << 16);
}
// round TWO independent f32 to bf16 in ONE v_cvt_pk_bf16_f32
__device__ __forceinline__ void bfr2(float& a, float& b) {
  unsigned r;
  asm("v_cvt_pk_bf16_f32 %0, %1, %2" : "=v"(r) : "v"(a), "v"(b));
  a = __uint_as_float(r << 16);
  b = __uint_as_float(r & 0xffff0000u);
}
}  // namespace

// static device scratch (all bf16-valued f32)
__device__ float g_h1[N_NODES * HID];
__device__ float g_r1[N_NODES * HID];
__device__ float g_h2[N_NODES * NC];
__device__ float g_sq1[N_NODES * D];
__device__ float g_sq2[N_NODES * D];
__device__ float g_sf1[N_NODES];
__device__ float g_sf2[N_NODES];
__device__ float g_w1b[F_IN * HID];   // pre-rounded W1

// pre-round W1 (bfr(bfr(w)) == bfr(w) -> exact-neutral)
__global__ __launch_bounds__(256, 8) void k_prew(const float* __restrict__ W1) {
  int g = blockIdx.x * blockDim.x + threadIdx.x;
  if (g < F_IN * HID) g_w1b[g] = bfr(W1[g]);
}

// h1: 8 nodes/block (64 threads), x rows staged pre-rounded in LDS (padded stride),
// 2 chains/thread; W from pre-rounded global table.
__global__ __launch_bounds__(64, 8) void k_lin1(const float* __restrict__ x,
                                                const float* __restrict__ b1) {
  constexpr int NB = 8;
  constexpr int XS = F_IN + 4;  // 516: 16B-aligned rows, banks spread
  __shared__ float xs[NB * XS];
  int t = threadIdx.x;
  int i0 = blockIdx.x * NB;
  const float4* xsrc = reinterpret_cast<const float4*>(x + (size_t)i0 * F_IN);
  for (int e = t; e < NB * (F_IN / 4); e += 64) {
    int node = e >> 7, off = e & 127;
    float4 v = xsrc[node * 128 + off];
    bfr2(v.x, v.y); bfr2(v.z, v.w);
    reinterpret_cast<float4*>(xs + node * XS)[off] = v;
  }
  __syncthreads();
  int j = t & 15, g = t >> 4;
  const float* x0 = xs + (2 * g) * XS;
  const float* x1 = xs + (2 * g + 1) * XS;
  float a0 = 0.f, a1 = 0.f;
#pragma unroll 4
  for (int k = 0; k < F_IN; ++k) {
    float wk = g_w1b[k * HID + j];
    float p0 = x0[k] * wk, p1 = x1[k] * wk;
    bfr2(p0, p1);
    float s0 = a0 + p0, s1 = a1 + p1;
    bfr2(s0, s1);
    a0 = s0; a1 = s1;
  }
  float bb = bfr(b1[j]);
  g_h1[(i0 + 2 * g) * HID + j] = bfr(a0 + bb);
  g_h1[(i0 + 2 * g + 1) * HID + j] = bfr(a1 + bb);
}

__global__ __launch_bounds__(256, 8) void k_lin2(const float* __restrict__ W2,
                                                 const float* __restrict__ b2) {
  int g = blockIdx.x * blockDim.x + threadIdx.x;
  if (g >= N_NODES * NC) return;
  int i = g >> 5, j = g & 31;
  float acc = 0.f;
#pragma unroll
  for (int k = 0; k < HID; ++k)
    acc = bfr(acc + bfr(g_r1[i * HID + k] * bfr(W2[k * NC + j])));
  g_h2[g] = bfr(acc + bfr(b2[j]));
}

// Per node i (one wave): tile, sq, self-kernel mean (5 paired chains), aggregation.
template <int H, bool LOGSM>
__global__ __launch_bounds__(64, 6) void k_build(
    const float* __restrict__ hpre, const int* __restrict__ row0,
    float* __restrict__ selfm, float* __restrict__ sqb,
    float* __restrict__ relu_out, float* __restrict__ out0) {
  constexpr int HS = H + 1;
  __shared__ int nidx[D];
  __shared__ __align__(16) float T[D * HS];
  __shared__ float sq[D];
  __shared__ float sterm[D * D];
  __shared__ float earr[32];
  __shared__ float lsv;
  int i = blockIdx.x, t = threadIdx.x;  // 0..63
  if (t < D) nidx[t] = (t < DEG) ? row0[i * DEG + t] : i;
  __syncthreads();
  for (int e = t; e < D * H; e += 64) {
    int d = e / H, h = e - d * H;
    T[d * HS + h] = hpre[(size_t)nidx[d] * H + h];
  }
  __syncthreads();
  if (t < D) {
    float s = 0.f;
#pragma unroll
    for (int h = 0; h < H; ++h) { float v = T[t * HS + h]; s = bfr(s + bfr(v * v)); }
    sq[t] = s;
    sqb[i * D + t] = s;
  }
  __syncthreads();
  {
    constexpr int M = (D * D + 63) / 64;  // 5
    float dots[M];
    int pa[M], pb[M];
#pragma unroll
    for (int m = 0; m < M; ++m) {
      int p = t + 64 * m;
      dots[m] = 0.f;
      pa[m] = (p < D * D) ? (p / D) : 0;
      pb[m] = (p < D * D) ? (p - (p / D) * D) : 0;
    }
#pragma unroll
    for (int q = 0; q < H; ++q) {
      float p0 = T[pa[0] * HS + q] * T[pb[0] * HS + q];
      float p1 = T[pa[1] * HS + q] * T[pb[1] * HS + q];
      float p2 = T[pa[2] * HS + q] * T[pb[2] * HS + q];
      float p3 = T[pa[3] * HS + q] * T[pb[3] * HS + q];
      float p4 = T[pa[4] * HS + q] * T[pb[4] * HS + q];
      bfr2(p0, p1); bfr2(p2, p3); p4 = bfr(p4);
      float s0 = dots[0] + p0, s1 = dots[1] + p1, s2 = dots[2] + p2,
            s3 = dots[3] + p3, s4 = dots[4] + p4;
      bfr2(s0, s1); bfr2(s2, s3); s4 = bfr(s4);
      dots[0] = s0; dots[1] = s1; dots[2] = s2; dots[3] = s3; dots[4] = s4;
    }
#pragma unroll
    for (int m = 0; m < M; ++m) {
      int p = t + 64 * m;
      if (p < D * D) {
        float d2 = bfr(bfr(sq[pa[m]] + sq[pb[m]]) - 2.f * dots[m]);  // 2*bf16 exact
        float arg = bfr((-d2) / SIGB);
        sterm[p] = bfr(expf(arg));
      }
    }
  }
  __syncthreads();
  if (t == 0) {
    float s = 0.f;
#pragma unroll 1
    for (int p = 0; p < D * D; ++p) s = bfr(s + sterm[p]);
    selfm[i] = bfr(s / 289.0f);
  }
  if constexpr (!LOGSM) {
    if (t < H) {
      float acc = 0.f;
#pragma unroll
      for (int d = 0; d < DEG; ++d) acc = bfr(acc + bfr(NORMB * T[d * HS + t]));
      acc = bfr(acc + bfr(NORMB * T[DEG * HS + t]));
      relu_out[i * H + t] = fmaxf(acc, 0.f);
    }
  } else {
    int j = t & 31;
    float v = 0.f;
#pragma unroll
    for (int d = 0; d < DEG; ++d) v = bfr(v + bfr(NORMB * T[d * HS + j]));
    v = bfr(v + bfr(NORMB * T[DEG * HS + j]));
    float m = v;
#pragma unroll
    for (int off = 32; off; off >>= 1) m = fmaxf(m, __shfl_xor(m, off));
    float sh = bfr(v - m);
    if (t < 32) earr[t] = bfr(expf(sh));
    __syncthreads();
    if (t == 0) {
      float s = 0.f;
#pragma unroll 1
      for (int q = 0; q < 32; ++q) s = bfr(s + earr[q]);
      lsv = bfr(logf(s));
    }
    __syncthreads();
    if (t < 32) out0[i * 32 + t] = bfr(sh - lsv);
  }
}

// cross body for ONE col-node group (u = 0..287 within group)
template <int H>
__device__ __forceinline__ void cross_body(int c, int u, float* sm,
                                           const float* __restrict__ hpre,
                                           const float* __restrict__ sqb,
                                           const float* __restrict__ selfm,
                                           const int* __restrict__ row0,
                                           float* __restrict__ outm) {
  constexpr int STQ = D + 1;  // 18
  float* hcT = sm;            // [H][18]
  float* sqc = sm + 576;
  float* cterm = sm + 593;    // [16][289]
  for (int e = u; e < D * H; e += 288) {
    int d = e / H, h = e - d * H;
    int idx = (d < DEG) ? row0[c * DEG + d] : c;
    hcT[h * STQ + d] = hpre[(size_t)idx * H + h];
  }
  if (u < D) sqc[u] = sqb[c * D + u];
  __syncthreads();
  if (u < DEG * D) {
    int k = u / D, a = u - k * D;
    int r = row0[c * DEG + k];
    int idx = (a < DEG) ? row0[r * DEG + a] : r;
    const float4* hr4 = reinterpret_cast<const float4*>(hpre + (size_t)idx * H);
    float rv[H];
#pragma unroll
    for (int q4 = 0; q4 < H / 4; ++q4) {
      float4 v = hr4[q4];
      rv[q4 * 4 + 0] = v.x; rv[q4 * 4 + 1] = v.y;
      rv[q4 * 4 + 2] = v.z; rv[q4 * 4 + 3] = v.w;
    }
    float sqra = sqb[r * D + a];
    float dotv[D];
    {
      float rq = rv[0];
#pragma unroll
      for (int b = 0; b < DEG; b += 2) {
        float2 h2 = *reinterpret_cast<const float2*>(&hcT[b]);
        float p0 = rq * h2.x, p1 = rq * h2.y;
        bfr2(p0, p1);
        dotv[b] = p0; dotv[b + 1] = p1;
      }
      dotv[16] = bfr(rq * hcT[16]);
    }
#pragma unroll
    for (int q = 1; q < H; ++q) {
      float rq = rv[q];
      const float* rowq = &hcT[q * STQ];
#pragma unroll
      for (int b = 0; b < DEG; b += 2) {
        float2 h2 = *reinterpret_cast<const float2*>(&rowq[b]);
        float p0 = rq * h2.x, p1 = rq * h2.y;
        bfr2(p0, p1);
        float s0 = dotv[b] + p0, s1 = dotv[b + 1] + p1;
        bfr2(s0, s1);
        dotv[b] = s0; dotv[b + 1] = s1;
      }
      dotv[16] = bfr(dotv[16] + bfr(rq * rowq[16]));
    }
    float* out_t = cterm + k * (D * D) + a * D;
#pragma unroll
    for (int b = 0; b < DEG; b += 2) {
      float S0 = sqra + sqc[b], S1 = sqra + sqc[b + 1];
      bfr2(S0, S1);
      float d20 = S0 - 2.f * dotv[b], d21 = S1 - 2.f * dotv[b + 1];
      bfr2(d20, d21);
      float a0 = (-d20) / SIGB, a1 = (-d21) / SIGB;
      bfr2(a0, a1);
      float e0 = expf(a0), e1 = expf(a1);
      bfr2(e0, e1);
      out_t[b] = e0; out_t[b + 1] = e1;
    }
    {
      float S = bfr(sqra + sqc[16]);
      float d2 = bfr(S - 2.f * dotv[16]);
      float arg = bfr((-d2) / SIGB);
      out_t[16] = bfr(expf(arg));
    }
  }
  __syncthreads();
  if (u < DEG) {
    const float* src = cterm + u * (D * D);
    float s = 0.f;
#pragma unroll 1
    for (int p = 0; p < D * D; ++p) s = bfr(s + src[p]);
    float cross = bfr(s / 289.0f);
    int r = row0[c * DEG + u];
    outm[c * DEG + u] = bfr(bfr(selfm[r] + selfm[c]) - 2.f * cross);
  }
  if (u == DEG) outm[E0 + c] = 0.0f;  // self-loop: identical chains -> exactly 0
}

// merged cross: blocks [0,5000) = layer1 (H=16), [5000,10000) = layer2 (H=32);
// each block covers 2 col-nodes (groups of 288 threads, 272 active).
__global__ __launch_bounds__(576, 5) void k_cross_all(
    const float* __restrict__ h1, const float* __restrict__ sq1,
    const float* __restrict__ sf1, float* __restrict__ out1,
    const float* __restrict__ h2, const float* __restrict__ sq2,
    const float* __restrict__ sf2, float* __restrict__ out2,
    const int* __restrict__ row0) {
  __shared__ float sm[2 * 5248];  // 41.98 KB
  int t = threadIdx.x;
  int g = (t >= 288) ? 1 : 0;
  int u = t - g * 288;
  int b = blockIdx.x;
  if (b < N_NODES / 2) {
    cross_body<HID>(b * 2 + g, u, sm + g * 5248, h1, sq1, sf1, row0, out1);
  } else {
    cross_body<NC>((b - N_NODES / 2) * 2 + g, u, sm + g * 5248, h2, sq2, sf2, row0, out2);
  }
}

extern "C" void kernel_launch(void* const* d_in, const int* in_sizes, int n_in,
                              void* d_out, int out_size, void* d_ws, size_t ws_size,
                              hipStream_t stream) {
  const float* x  = (const float*)d_in[0];
  const int* edge_index = (const int*)d_in[1];
  const float* W1 = (const float*)d_in[2];
  const float* b1 = (const float*)d_in[3];
  const float* W2 = (const float*)d_in[4];
  const float* b2 = (const float*)d_in[5];
  const int* row0 = edge_index;
  (void)d_ws; (void)ws_size;

  float *h1, *r1, *h2, *sq1, *sq2, *sf1, *sf2;
  hipGetSymbolAddress((void**)&h1,  HIP_SYMBOL(g_h1));
  hipGetSymbolAddress((void**)&r1,  HIP_SYMBOL(g_r1));
  hipGetSymbolAddress((void**)&h2,  HIP_SYMBOL(g_h2));
  hipGetSymbolAddress((void**)&sq1, HIP_SYMBOL(g_sq1));
  hipGetSymbolAddress((void**)&sq2, HIP_SYMBOL(g_sq2));
  hipGetSymbolAddress((void**)&sf1, HIP_SYMBOL(g_sf1));
  hipGetSymbolAddress((void**)&sf2, HIP_SYMBOL(g_sf2));

  float* out0 = (float*)d_out;
  float* out1 = out0 + N_NODES * NC;
  float* out2 = out1 + (E0 + N_NODES);

  k_prew<<<(F_IN * HID + 255) / 256, 256, 0, stream>>>(W1);
  k_lin1<<<N_NODES / 8, 64, 0, stream>>>(x, b1);
  k_build<HID, false><<<N_NODES, 64, 0, stream>>>(h1, row0, sf1, sq1, r1, nullptr);
  k_lin2<<<(N_NODES * NC + 255) / 256, 256, 0, stream>>>(W2, b2);
  k_build<NC, true><<<N_NODES, 64, 0, stream>>>(h2, row0, sf2, sq2, nullptr, out0);
  k_cross_all<<<N_NODES, 576, 0, stream>>>(h1, sq1, sf1, out1, h2, sq2, sf2, out2, row0);
}

// Round 10
// 705.851 us; speedup vs baseline: 1.1124x; 1.1124x over previous
//
#include <hip/hip_runtime.h>

namespace {
constexpr int N_NODES = 10000;
constexpr int DEG = 16;
constexpr int D = DEG + 1;            // 17 neighbors incl self-loop
constexpr int F_IN = 512;
constexpr int HID = 16;
constexpr int NC = 32;
constexpr int E0 = N_NODES * DEG;     // 160000
constexpr float SIGB  = 0.10009765625f;    // bf16(0.1)
constexpr float NORMB = 0.058837890625f;   // bf16(bf16(17^-0.5)^2)

// RNE f32->bf16 via gfx950 HW cvt
__device__ __forceinline__ float bfr(float v) {
  unsigned r;
  asm("v_cvt_pk_bf16_f32 %0, %1, %2" : "=v"(r) : "v"(v), "v"(v));
  return __uint_as_float(r << 16);
}
// round TWO independent f32 to bf16 in ONE v_cvt_pk_bf16_f32
__device__ __forceinline__ void bfr2(float& a, float& b) {
  unsigned r;
  asm("v_cvt_pk_bf16_f32 %0, %1, %2" : "=v"(r) : "v"(a), "v"(b));
  a = __uint_as_float(r << 16);
  b = __uint_as_float(r & 0xffff0000u);
}
}  // namespace

// static device scratch (all bf16-valued f32)
__device__ float g_h1[N_NODES * HID];
__device__ float g_r1[N_NODES * HID];
__device__ float g_h2[N_NODES * NC];
__device__ float g_sq1[N_NODES * D];
__device__ float g_sq2[N_NODES * D];
__device__ float g_sf1[N_NODES];
__device__ float g_sf2[N_NODES];
__device__ float g_w1b[F_IN * HID];   // pre-rounded W1

// pre-round W1 (bfr(bfr(w)) == bfr(w) -> exact-neutral)
__global__ __launch_bounds__(256, 8) void k_prew(const float* __restrict__ W1) {
  int g = blockIdx.x * blockDim.x + threadIdx.x;
  if (g < F_IN * HID) g_w1b[g] = bfr(W1[g]);
}

// h1: 8 nodes/block (64 threads), x rows staged pre-rounded in LDS, 2 chains/thread.
__global__ __launch_bounds__(64, 8) void k_lin1(const float* __restrict__ x,
                                                const float* __restrict__ b1) {
  constexpr int NB = 8;
  constexpr int XS = F_IN + 4;
  __shared__ float xs[NB * XS];
  int t = threadIdx.x;
  int i0 = blockIdx.x * NB;
  const float4* xsrc = reinterpret_cast<const float4*>(x + (size_t)i0 * F_IN);
  for (int e = t; e < NB * (F_IN / 4); e += 64) {
    int node = e >> 7, off = e & 127;
    float4 v = xsrc[node * 128 + off];
    bfr2(v.x, v.y); bfr2(v.z, v.w);
    reinterpret_cast<float4*>(xs + node * XS)[off] = v;
  }
  __syncthreads();
  int j = t & 15, g = t >> 4;
  const float* x0 = xs + (2 * g) * XS;
  const float* x1 = xs + (2 * g + 1) * XS;
  float a0 = 0.f, a1 = 0.f;
#pragma unroll 4
  for (int k = 0; k < F_IN; ++k) {
    float wk = g_w1b[k * HID + j];
    float p0 = x0[k] * wk, p1 = x1[k] * wk;
    bfr2(p0, p1);
    float s0 = a0 + p0, s1 = a1 + p1;
    bfr2(s0, s1);
    a0 = s0; a1 = s1;
  }
  float bb = bfr(b1[j]);
  g_h1[(i0 + 2 * g) * HID + j] = bfr(a0 + bb);
  g_h1[(i0 + 2 * g + 1) * HID + j] = bfr(a1 + bb);
}

__global__ __launch_bounds__(256, 8) void k_lin2(const float* __restrict__ W2,
                                                 const float* __restrict__ b2) {
  int g = blockIdx.x * blockDim.x + threadIdx.x;
  if (g >= N_NODES * NC) return;
  int i = g >> 5, j = g & 31;
  float acc = 0.f;
#pragma unroll
  for (int k = 0; k < HID; ++k)
    acc = bfr(acc + bfr(g_r1[i * HID + k] * bfr(W2[k * NC + j])));
  g_h2[g] = bfr(acc + bfr(b2[j]));
}

// Per node i (one wave): tile, sq, self-kernel mean (5 paired chains), aggregation.
// (round-8 verified form: libm expf, /SIGB, sequential tails)
template <int H, bool LOGSM>
__global__ __launch_bounds__(64, 6) void k_build(
    const float* __restrict__ hpre, const int* __restrict__ row0,
    float* __restrict__ selfm, float* __restrict__ sqb,
    float* __restrict__ relu_out, float* __restrict__ out0) {
  constexpr int HS = H + 1;
  __shared__ int nidx[D];
  __shared__ __align__(16) float T[D * HS];
  __shared__ float sq[D];
  __shared__ float sterm[D * D];
  __shared__ float earr[32];
  __shared__ float lsv;
  int i = blockIdx.x, t = threadIdx.x;  // 0..63
  if (t < D) nidx[t] = (t < DEG) ? row0[i * DEG + t] : i;
  __syncthreads();
  for (int e = t; e < D * H; e += 64) {
    int d = e / H, h = e - d * H;
    T[d * HS + h] = hpre[(size_t)nidx[d] * H + h];
  }
  __syncthreads();
  if (t < D) {
    float s = 0.f;
#pragma unroll
    for (int h = 0; h < H; ++h) { float v = T[t * HS + h]; s = bfr(s + bfr(v * v)); }
    sq[t] = s;
    sqb[i * D + t] = s;
  }
  __syncthreads();
  {
    constexpr int M = (D * D + 63) / 64;  // 5
    float dots[M];
    int pa[M], pb[M];
#pragma unroll
    for (int m = 0; m < M; ++m) {
      int p = t + 64 * m;
      dots[m] = 0.f;
      pa[m] = (p < D * D) ? (p / D) : 0;
      pb[m] = (p < D * D) ? (p - (p / D) * D) : 0;
    }
#pragma unroll
    for (int q = 0; q < H; ++q) {
      float p0 = T[pa[0] * HS + q] * T[pb[0] * HS + q];
      float p1 = T[pa[1] * HS + q] * T[pb[1] * HS + q];
      float p2 = T[pa[2] * HS + q] * T[pb[2] * HS + q];
      float p3 = T[pa[3] * HS + q] * T[pb[3] * HS + q];
      float p4 = T[pa[4] * HS + q] * T[pb[4] * HS + q];
      bfr2(p0, p1); bfr2(p2, p3); p4 = bfr(p4);
      float s0 = dots[0] + p0, s1 = dots[1] + p1, s2 = dots[2] + p2,
            s3 = dots[3] + p3, s4 = dots[4] + p4;
      bfr2(s0, s1); bfr2(s2, s3); s4 = bfr(s4);
      dots[0] = s0; dots[1] = s1; dots[2] = s2; dots[3] = s3; dots[4] = s4;
    }
#pragma unroll
    for (int m = 0; m < M; ++m) {
      int p = t + 64 * m;
      if (p < D * D) {
        float d2 = bfr(bfr(sq[pa[m]] + sq[pb[m]]) - 2.f * dots[m]);  // 2*bf16 exact
        float arg = bfr((-d2) / SIGB);
        sterm[p] = bfr(expf(arg));
      }
    }
  }
  __syncthreads();
  if (t == 0) {
    float s = 0.f;
#pragma unroll 1
    for (int p = 0; p < D * D; ++p) s = bfr(s + sterm[p]);
    selfm[i] = bfr(s / 289.0f);
  }
  if constexpr (!LOGSM) {
    if (t < H) {
      float acc = 0.f;
#pragma unroll
      for (int d = 0; d < DEG; ++d) acc = bfr(acc + bfr(NORMB * T[d * HS + t]));
      acc = bfr(acc + bfr(NORMB * T[DEG * HS + t]));
      relu_out[i * H + t] = fmaxf(acc, 0.f);
    }
  } else {
    int j = t & 31;
    float v = 0.f;
#pragma unroll
    for (int d = 0; d < DEG; ++d) v = bfr(v + bfr(NORMB * T[d * HS + j]));
    v = bfr(v + bfr(NORMB * T[DEG * HS + j]));
    float m = v;
#pragma unroll
    for (int off = 32; off; off >>= 1) m = fmaxf(m, __shfl_xor(m, off));
    float sh = bfr(v - m);
    if (t < 32) earr[t] = bfr(expf(sh));
    __syncthreads();
    if (t == 0) {
      float s = 0.f;
#pragma unroll 1
      for (int q = 0; q < 32; ++q) s = bfr(s + earr[q]);
      lsv = bfr(logf(s));
    }
    __syncthreads();
    if (t < 32) out0[i * 32 + t] = bfr(sh - lsv);
  }
}

// Per col-node c: round-7 verified k_cross verbatim; ONLY change: launch_bounds(320,4)
// so the allocator may keep rv[]/dotv[] resident (cap 128 VGPRs vs default 32).
template <int H>
__global__ __launch_bounds__(320, 4) void k_cross(
    const float* __restrict__ hpre, const float* __restrict__ sqb,
    const float* __restrict__ selfm, const int* __restrict__ row0,
    float* __restrict__ outm) {
  constexpr int STQ = D + 1;  // 18: even stride -> 8B-aligned pairs at even b
  __shared__ __align__(16) float hcT[H * STQ];
  __shared__ float sqc[D];
  __shared__ float cterm[DEG * D * D];
  int c = blockIdx.x, t = threadIdx.x;  // 0..319
  for (int e = t; e < D * H; e += 320) {
    int d = e / H, h = e - d * H;
    int idx = (d < DEG) ? row0[c * DEG + d] : c;
    hcT[h * STQ + d] = hpre[(size_t)idx * H + h];  // transposed: [q][b]
  }
  if (t < D) sqc[t] = sqb[c * D + t];
  __syncthreads();
  if (t < DEG * D) {
    int k = t / D, a = t - k * D;
    int r = row0[c * DEG + k];
    int idx = (a < DEG) ? row0[r * DEG + a] : r;
    const float4* hr4 = reinterpret_cast<const float4*>(hpre + (size_t)idx * H);
    float rv[H];
#pragma unroll
    for (int q4 = 0; q4 < H / 4; ++q4) {
      float4 v = hr4[q4];
      rv[q4 * 4 + 0] = v.x; rv[q4 * 4 + 1] = v.y;
      rv[q4 * 4 + 2] = v.z; rv[q4 * 4 + 3] = v.w;
    }
    float sqra = sqb[r * D + a];
    float dotv[D];
    {  // q = 0: seed chains (bfr(0+p) == p)
      float rq = rv[0];
#pragma unroll
      for (int b = 0; b < DEG; b += 2) {
        float2 h2 = *reinterpret_cast<const float2*>(&hcT[b]);
        float p0 = rq * h2.x, p1 = rq * h2.y;
        bfr2(p0, p1);
        dotv[b] = p0; dotv[b + 1] = p1;
      }
      dotv[16] = bfr(rq * hcT[16]);
    }
#pragma unroll
    for (int q = 1; q < H; ++q) {
      float rq = rv[q];
      const float* rowq = &hcT[q * STQ];
#pragma unroll
      for (int b = 0; b < DEG; b += 2) {
        float2 h2 = *reinterpret_cast<const float2*>(&rowq[b]);
        float p0 = rq * h2.x, p1 = rq * h2.y;
        bfr2(p0, p1);
        float s0 = dotv[b] + p0, s1 = dotv[b + 1] + p1;
        bfr2(s0, s1);
        dotv[b] = s0; dotv[b + 1] = s1;
      }
      dotv[16] = bfr(dotv[16] + bfr(rq * rowq[16]));
    }
    float* out_t = cterm + k * (D * D) + a * D;
#pragma unroll
    for (int b = 0; b < DEG; b += 2) {
      float S0 = sqra + sqc[b], S1 = sqra + sqc[b + 1];
      bfr2(S0, S1);
      float d20 = S0 - 2.f * dotv[b], d21 = S1 - 2.f * dotv[b + 1];
      bfr2(d20, d21);
      float a0 = (-d20) / SIGB, a1 = (-d21) / SIGB;
      bfr2(a0, a1);
      float e0 = expf(a0), e1 = expf(a1);
      bfr2(e0, e1);
      out_t[b] = e0; out_t[b + 1] = e1;
    }
    {
      float S = bfr(sqra + sqc[16]);
      float d2 = bfr(S - 2.f * dotv[16]);
      float arg = bfr((-d2) / SIGB);
      out_t[16] = bfr(expf(arg));
    }
  }
  __syncthreads();
  if (t < DEG) {
    const float* src = cterm + t * (D * D);
    float s = 0.f;
#pragma unroll 1
    for (int p = 0; p < D * D; ++p) s = bfr(s + src[p]);
    float cross = bfr(s / 289.0f);
    int r = row0[c * DEG + t];
    outm[c * DEG + t] = bfr(bfr(selfm[r] + selfm[c]) - 2.f * cross);
  }
  if (t == DEG) outm[E0 + c] = 0.0f;  // self-loop: identical chains -> exactly 0
}

extern "C" void kernel_launch(void* const* d_in, const int* in_sizes, int n_in,
                              void* d_out, int out_size, void* d_ws, size_t ws_size,
                              hipStream_t stream) {
  const float* x  = (const float*)d_in[0];
  const int* edge_index = (const int*)d_in[1];
  const float* W1 = (const float*)d_in[2];
  const float* b1 = (const float*)d_in[3];
  const float* W2 = (const float*)d_in[4];
  const float* b2 = (const float*)d_in[5];
  const int* row0 = edge_index;
  (void)d_ws; (void)ws_size;

  float *h1, *r1, *h2, *sq1, *sq2, *sf1, *sf2;
  hipGetSymbolAddress((void**)&h1,  HIP_SYMBOL(g_h1));
  hipGetSymbolAddress((void**)&r1,  HIP_SYMBOL(g_r1));
  hipGetSymbolAddress((void**)&h2,  HIP_SYMBOL(g_h2));
  hipGetSymbolAddress((void**)&sq1, HIP_SYMBOL(g_sq1));
  hipGetSymbolAddress((void**)&sq2, HIP_SYMBOL(g_sq2));
  hipGetSymbolAddress((void**)&sf1, HIP_SYMBOL(g_sf1));
  hipGetSymbolAddress((void**)&sf2, HIP_SYMBOL(g_sf2));

  float* out0 = (float*)d_out;
  float* out1 = out0 + N_NODES * NC;
  float* out2 = out1 + (E0 + N_NODES);

  k_prew<<<(F_IN * HID + 255) / 256, 256, 0, stream>>>(W1);
  k_lin1<<<N_NODES / 8, 64, 0, stream>>>(x, b1);
  k_build<HID, false><<<N_NODES, 64, 0, stream>>>(h1, row0, sf1, sq1, r1, nullptr);
  k_cross<HID><<<N_NODES, 320, 0, stream>>>(h1, sq1, sf1, row0, out1);
  k_lin2<<<(N_NODES * NC + 255) / 256, 256, 0, stream>>>(W2, b2);
  k_build<NC, true><<<N_NODES, 64, 0, stream>>>(h2, row0, sf2, sq2, nullptr, out0);
  k_cross<NC><<<N_NODES, 320, 0, stream>>>(h2, sq2, sf2, row0, out2);
}

// Round 12
// 637.748 us; speedup vs baseline: 1.2312x; 1.1068x over previous
//
#include <hip/hip_runtime.h>

namespace {
constexpr int N_NODES = 10000;
constexpr int DEG = 16;
constexpr int D = DEG + 1;            // 17 neighbors incl self-loop
constexpr int F_IN = 512;
constexpr int HID = 16;
constexpr int NC = 32;
constexpr int E0 = N_NODES * DEG;     // 160000
constexpr float SIGB  = 0.10009765625f;    // bf16(0.1)
constexpr float NORMB = 0.058837890625f;   // bf16(bf16(17^-0.5)^2)

// RNE f32->bf16 via gfx950 HW cvt
__device__ __forceinline__ float bfr(float v) {
  unsigned r;
  asm("v_cvt_pk_bf16_f32 %0, %1, %2" : "=v"(r) : "v"(v), "v"(v));
  return __uint_as_float(r << 16);
}
// round TWO independent f32 to bf16 in ONE v_cvt_pk_bf16_f32
__device__ __forceinline__ void bfr2(float& a, float& b) {
  unsigned r;
  asm("v_cvt_pk_bf16_f32 %0, %1, %2" : "=v"(r) : "v"(a), "v"(b));
  a = __uint_as_float(r << 16);
  b = __uint_as_float(r & 0xffff0000u);
}
}  // namespace

// static device scratch (all bf16-valued f32)
__device__ float g_h1[N_NODES * HID];
__device__ float g_r1[N_NODES * HID];
__device__ float g_h2[N_NODES * NC];
__device__ float g_sq1[N_NODES * D];
__device__ float g_sq2[N_NODES * D];
__device__ float g_sf1[N_NODES];
__device__ float g_sf2[N_NODES];
__device__ float g_w1b[F_IN * HID];   // pre-rounded W1
__device__ float g_tab[65536];        // d2(bf16 bits) -> bfr(expf(bfr((-d2)/SIGB)))

// Build the exp table with the EXACT round-10 instruction sequence -> lookup is
// bit-identical to computing, for every possible bf16 d2 pattern (incl inf/NaN).
__global__ __launch_bounds__(256, 8) void k_tab() {
  int g = blockIdx.x * blockDim.x + threadIdx.x;  // 0..65535
  float d2 = __uint_as_float(((unsigned)g) << 16);
  float arg = bfr((-d2) / SIGB);
  g_tab[g] = bfr(expf(arg));
}

// pre-round W1 (bfr(bfr(w)) == bfr(w) -> exact-neutral)
__global__ __launch_bounds__(256, 8) void k_prew(const float* __restrict__ W1) {
  int g = blockIdx.x * blockDim.x + threadIdx.x;
  if (g < F_IN * HID) g_w1b[g] = bfr(W1[g]);
}

// h1: 8 nodes/block (64 threads), x rows staged pre-rounded in LDS, 2 chains/thread.
__global__ __launch_bounds__(64, 8) void k_lin1(const float* __restrict__ x,
                                                const float* __restrict__ b1) {
  constexpr int NB = 8;
  constexpr int XS = F_IN + 4;
  __shared__ float xs[NB * XS];
  int t = threadIdx.x;
  int i0 = blockIdx.x * NB;
  const float4* xsrc = reinterpret_cast<const float4*>(x + (size_t)i0 * F_IN);
  for (int e = t; e < NB * (F_IN / 4); e += 64) {
    int node = e >> 7, off = e & 127;
    float4 v = xsrc[node * 128 + off];
    bfr2(v.x, v.y); bfr2(v.z, v.w);
    reinterpret_cast<float4*>(xs + node * XS)[off] = v;
  }
  __syncthreads();
  int j = t & 15, g = t >> 4;
  const float* x0 = xs + (2 * g) * XS;
  const float* x1 = xs + (2 * g + 1) * XS;
  float a0 = 0.f, a1 = 0.f;
#pragma unroll 4
  for (int k = 0; k < F_IN; ++k) {
    float wk = g_w1b[k * HID + j];
    float p0 = x0[k] * wk, p1 = x1[k] * wk;
    bfr2(p0, p1);
    float s0 = a0 + p0, s1 = a1 + p1;
    bfr2(s0, s1);
    a0 = s0; a1 = s1;
  }
  float bb = bfr(b1[j]);
  g_h1[(i0 + 2 * g) * HID + j] = bfr(a0 + bb);
  g_h1[(i0 + 2 * g + 1) * HID + j] = bfr(a1 + bb);
}

__global__ __launch_bounds__(256, 8) void k_lin2(const float* __restrict__ W2,
                                                 const float* __restrict__ b2) {
  int g = blockIdx.x * blockDim.x + threadIdx.x;
  if (g >= N_NODES * NC) return;
  int i = g >> 5, j = g & 31;
  float acc = 0.f;
#pragma unroll
  for (int k = 0; k < HID; ++k)
    acc = bfr(acc + bfr(g_r1[i * HID + k] * bfr(W2[k * NC + j])));
  g_h2[g] = bfr(acc + bfr(b2[j]));
}

// Per node i (one wave): tile, sq, self-kernel mean (5 paired chains), aggregation.
template <int H, bool LOGSM>
__global__ __launch_bounds__(64, 6) void k_build(
    const float* __restrict__ hpre, const int* __restrict__ row0,
    float* __restrict__ selfm, float* __restrict__ sqb,
    float* __restrict__ relu_out, float* __restrict__ out0) {
  constexpr int HS = H + 1;
  __shared__ int nidx[D];
  __shared__ __align__(16) float T[D * HS];
  __shared__ float sq[D];
  __shared__ float sterm[D * D];
  __shared__ float earr[32];
  __shared__ float lsv;
  int i = blockIdx.x, t = threadIdx.x;  // 0..63
  if (t < D) nidx[t] = (t < DEG) ? row0[i * DEG + t] : i;
  __syncthreads();
  for (int e = t; e < D * H; e += 64) {
    int d = e / H, h = e - d * H;
    T[d * HS + h] = hpre[(size_t)nidx[d] * H + h];
  }
  __syncthreads();
  if (t < D) {
    float s = 0.f;
#pragma unroll
    for (int h = 0; h < H; ++h) { float v = T[t * HS + h]; s = bfr(s + bfr(v * v)); }
    sq[t] = s;
    sqb[i * D + t] = s;
  }
  __syncthreads();
  {
    constexpr int M = (D * D + 63) / 64;  // 5
    float dots[M];
    int pa[M], pb[M];
#pragma unroll
    for (int m = 0; m < M; ++m) {
      int p = t + 64 * m;
      dots[m] = 0.f;
      pa[m] = (p < D * D) ? (p / D) : 0;
      pb[m] = (p < D * D) ? (p - (p / D) * D) : 0;
    }
#pragma unroll
    for (int q = 0; q < H; ++q) {
      float p0 = T[pa[0] * HS + q] * T[pb[0] * HS + q];
      float p1 = T[pa[1] * HS + q] * T[pb[1] * HS + q];
      float p2 = T[pa[2] * HS + q] * T[pb[2] * HS + q];
      float p3 = T[pa[3] * HS + q] * T[pb[3] * HS + q];
      float p4 = T[pa[4] * HS + q] * T[pb[4] * HS + q];
      bfr2(p0, p1); bfr2(p2, p3); p4 = bfr(p4);
      float s0 = dots[0] + p0, s1 = dots[1] + p1, s2 = dots[2] + p2,
            s3 = dots[3] + p3, s4 = dots[4] + p4;
      bfr2(s0, s1); bfr2(s2, s3); s4 = bfr(s4);
      dots[0] = s0; dots[1] = s1; dots[2] = s2; dots[3] = s3; dots[4] = s4;
    }
#pragma unroll
    for (int m = 0; m < M; ++m) {
      int p = t + 64 * m;
      if (p < D * D) {
        float d2 = bfr(bfr(sq[pa[m]] + sq[pb[m]]) - 2.f * dots[m]);  // 2*bf16 exact
        sterm[p] = g_tab[__float_as_uint(d2) >> 16];  // == bfr(expf(bfr(-d2/SIGB)))
      }
    }
  }
  __syncthreads();
  if (t == 0) {
    float s = 0.f;
#pragma unroll 1
    for (int p = 0; p < D * D; ++p) s = bfr(s + sterm[p]);
    selfm[i] = bfr(s / 289.0f);
  }
  if constexpr (!LOGSM) {
    if (t < H) {
      float acc = 0.f;
#pragma unroll
      for (int d = 0; d < DEG; ++d) acc = bfr(acc + bfr(NORMB * T[d * HS + t]));
      acc = bfr(acc + bfr(NORMB * T[DEG * HS + t]));
      relu_out[i * H + t] = fmaxf(acc, 0.f);
    }
  } else {
    int j = t & 31;
    float v = 0.f;
#pragma unroll
    for (int d = 0; d < DEG; ++d) v = bfr(v + bfr(NORMB * T[d * HS + j]));
    v = bfr(v + bfr(NORMB * T[DEG * HS + j]));
    float m = v;
#pragma unroll
    for (int off = 32; off; off >>= 1) m = fmaxf(m, __shfl_xor(m, off));
    float sh = bfr(v - m);
    if (t < 32) earr[t] = bfr(expf(sh));
    __syncthreads();
    if (t == 0) {
      float s = 0.f;
#pragma unroll 1
      for (int q = 0; q < 32; ++q) s = bfr(s + earr[q]);
      lsv = bfr(logf(s));
    }
    __syncthreads();
    if (t < 32) out0[i * 32 + t] = bfr(sh - lsv);
  }
}

// Per col-node c: round-10 verified k_cross; div+exp tail replaced by g_tab lookup
// (bit-identical by construction).
template <int H>
__global__ __launch_bounds__(320, 4) void k_cross(
    const float* __restrict__ hpre, const float* __restrict__ sqb,
    const float* __restrict__ selfm, const int* __restrict__ row0,
    float* __restrict__ outm) {
  constexpr int STQ = D + 1;  // 18: even stride -> 8B-aligned pairs at even b
  __shared__ __align__(16) float hcT[H * STQ];
  __shared__ float sqc[D];
  __shared__ float cterm[DEG * D * D];
  int c = blockIdx.x, t = threadIdx.x;  // 0..319
  for (int e = t; e < D * H; e += 320) {
    int d = e / H, h = e - d * H;
    int idx = (d < DEG) ? row0[c * DEG + d] : c;
    hcT[h * STQ + d] = hpre[(size_t)idx * H + h];  // transposed: [q][b]
  }
  if (t < D) sqc[t] = sqb[c * D + t];
  __syncthreads();
  if (t < DEG * D) {
    int k = t / D, a = t - k * D;
    int r = row0[c * DEG + k];
    int idx = (a < DEG) ? row0[r * DEG + a] : r;
    const float4* hr4 = reinterpret_cast<const float4*>(hpre + (size_t)idx * H);
    float rv[H];
#pragma unroll
    for (int q4 = 0; q4 < H / 4; ++q4) {
      float4 v = hr4[q4];
      rv[q4 * 4 + 0] = v.x; rv[q4 * 4 + 1] = v.y;
      rv[q4 * 4 + 2] = v.z; rv[q4 * 4 + 3] = v.w;
    }
    float sqra = sqb[r * D + a];
    float dotv[D];
    {  // q = 0: seed chains (bfr(0+p) == p)
      float rq = rv[0];
#pragma unroll
      for (int b = 0; b < DEG; b += 2) {
        float2 h2 = *reinterpret_cast<const float2*>(&hcT[b]);
        float p0 = rq * h2.x, p1 = rq * h2.y;
        bfr2(p0, p1);
        dotv[b] = p0; dotv[b + 1] = p1;
      }
      dotv[16] = bfr(rq * hcT[16]);
    }
#pragma unroll
    for (int q = 1; q < H; ++q) {
      float rq = rv[q];
      const float* rowq = &hcT[q * STQ];
#pragma unroll
      for (int b = 0; b < DEG; b += 2) {
        float2 h2 = *reinterpret_cast<const float2*>(&rowq[b]);
        float p0 = rq * h2.x, p1 = rq * h2.y;
        bfr2(p0, p1);
        float s0 = dotv[b] + p0, s1 = dotv[b + 1] + p1;
        bfr2(s0, s1);
        dotv[b] = s0; dotv[b + 1] = s1;
      }
      dotv[16] = bfr(dotv[16] + bfr(rq * rowq[16]));
    }
    float* out_t = cterm + k * (D * D) + a * D;
#pragma unroll
    for (int b = 0; b < DEG; b += 2) {
      float S0 = sqra + sqc[b], S1 = sqra + sqc[b + 1];
      bfr2(S0, S1);
      float d20 = S0 - 2.f * dotv[b], d21 = S1 - 2.f * dotv[b + 1];
      bfr2(d20, d21);
      out_t[b] = g_tab[__float_as_uint(d20) >> 16];
      out_t[b + 1] = g_tab[__float_as_uint(d21) >> 16];
    }
    {
      float S = bfr(sqra + sqc[16]);
      float d2 = bfr(S - 2.f * dotv[16]);
      out_t[16] = g_tab[__float_as_uint(d2) >> 16];
    }
  }
  __syncthreads();
  if (t < DEG) {
    const float* src = cterm + t * (D * D);
    float s = 0.f;
#pragma unroll 1
    for (int p = 0; p < D * D; ++p) s = bfr(s + src[p]);
    float cross = bfr(s / 289.0f);
    int r = row0[c * DEG + t];
    outm[c * DEG + t] = bfr(bfr(selfm[r] + selfm[c]) - 2.f * cross);
  }
  if (t == DEG) outm[E0 + c] = 0.0f;  // self-loop: identical chains -> exactly 0
}

extern "C" void kernel_launch(void* const* d_in, const int* in_sizes, int n_in,
                              void* d_out, int out_size, void* d_ws, size_t ws_size,
                              hipStream_t stream) {
  const float* x  = (const float*)d_in[0];
  const int* edge_index = (const int*)d_in[1];
  const float* W1 = (const float*)d_in[2];
  const float* b1 = (const float*)d_in[3];
  const float* W2 = (const float*)d_in[4];
  const float* b2 = (const float*)d_in[5];
  const int* row0 = edge_index;
  (void)d_ws; (void)ws_size;

  float *h1, *r1, *h2, *sq1, *sq2, *sf1, *sf2;
  hipGetSymbolAddress((void**)&h1,  HIP_SYMBOL(g_h1));
  hipGetSymbolAddress((void**)&r1,  HIP_SYMBOL(g_r1));
  hipGetSymbolAddress((void**)&h2,  HIP_SYMBOL(g_h2));
  hipGetSymbolAddress((void**)&sq1, HIP_SYMBOL(g_sq1));
  hipGetSymbolAddress((void**)&sq2, HIP_SYMBOL(g_sq2));
  hipGetSymbolAddress((void**)&sf1, HIP_SYMBOL(g_sf1));
  hipGetSymbolAddress((void**)&sf2, HIP_SYMBOL(g_sf2));

  float* out0 = (float*)d_out;
  float* out1 = out0 + N_NODES * NC;
  float* out2 = out1 + (E0 + N_NODES);

  k_tab<<<256, 256, 0, stream>>>();
  k_prew<<<(F_IN * HID + 255) / 256, 256, 0, stream>>>(W1);
  k_lin1<<<N_NODES / 8, 64, 0, stream>>>(x, b1);
  k_build<HID, false><<<N_NODES, 64, 0, stream>>>(h1, row0, sf1, sq1, r1, nullptr);
  k_cross<HID><<<N_NODES, 320, 0, stream>>>(h1, sq1, sf1, row0, out1);
  k_lin2<<<(N_NODES * NC + 255) / 256, 256, 0, stream>>>(W2, b2);
  k_build<NC, true><<<N_NODES, 64, 0, stream>>>(h2, row0, sf2, sq2, nullptr, out0);
  k_cross<NC><<<N_NODES, 320, 0, stream>>>(h2, sq2, sf2, row0, out2);
}